// Round 5
// baseline (1677.633 us; speedup 1.0000x reference)
//
#include <hip/hip_runtime.h>
#include <hip/hip_bf16.h>

// ChromaticTransportEvaluator — round 5: single persistent kernel.
// R4 post-mortem: total ~= 44 dispatches x ~10us fixed cost -> dispatch-count
// bound, not compute. Fuse everything into ONE kernel (grid 256x256, trivially
// co-resident) with a device-scope monotonic-counter global barrier.
// Phases: 0 oklab+minmax | 1 packK+hist+u-init | 2..41 sinkhorn half-iters
// (64p x 32j tile per wg, bf16 hi/lo MFMA, 3 terms) | 42 EMD | 43 upsample.
//
// mfma_f32_16x16x32_bf16 layouts (guide §3, m89-verified):
//   A[m][k]: m = lane&15, k = (lane>>4)*8 + reg
//   B[k][n]: n = lane&15, k = (lane>>4)*8 + reg
//   C/D:     col = lane&15, row = (lane>>4)*4 + reg

#define LAB_STRIDE 786432         // 4*3*256*256 floats per image-set
#define NWG 256

typedef __attribute__((ext_vector_type(8))) short short8;
typedef __attribute__((ext_vector_type(4))) short short4_t;
typedef __attribute__((ext_vector_type(4))) float floatx4;

__device__ __forceinline__ float hw_exp2(float x) { return __builtin_amdgcn_exp2f(x); }
__device__ __forceinline__ float hw_log2(float x) { return __builtin_amdgcn_logf(x); }

__device__ __forceinline__ unsigned enc_f(float f) {
    unsigned u = __float_as_uint(f);
    return (u & 0x80000000u) ? ~u : (u | 0x80000000u);
}
__device__ __forceinline__ float dec_f(unsigned k) {
    unsigned u = (k & 0x80000000u) ? (k ^ 0x80000000u) : ~k;
    return __uint_as_float(u);
}

__device__ __forceinline__ float s2lin(float x) {
    x = fminf(fmaxf(x, 0.f), 1.f);
    return (x <= 0.04045f) ? (x * (1.f / 12.92f))
                           : hw_exp2(2.4f * hw_log2((x + 0.055f) * (1.f / 1.055f)));
}
__device__ __forceinline__ float cbrt_fast(float l) {
    return hw_exp2(0.33333333333f * hw_log2(fmaxf(l, 1e-12f)));
}

__device__ __forceinline__ void lohi_img(const unsigned* mm, int img,
                                         float lo[3], float hi[3]) {
    for (int c = 0; c < 3; ++c) {
        float mn = dec_f(mm[img * 6 + c * 2 + 0]);
        float mx = dec_f(mm[img * 6 + c * 2 + 1]);
        float l = mn - 0.01f, h = mx + 0.01f;
        if (h - l < 1e-4f) { l -= 0.05f; h += 0.05f; }
        lo[c] = l; hi[c] = h;
    }
}

__device__ __forceinline__ unsigned bf16_rne(float f) {
    unsigned u = __float_as_uint(f);
    return (u + 0x7FFFu + ((u >> 16) & 1u)) >> 16;
}
__device__ __forceinline__ float bf16_to_f(unsigned short b) {
    return __uint_as_float(((unsigned)b) << 16);
}

// Monotonic global barrier: each wg arrives once per phase; spin until
// cnt >= NWG*phase. Device-scope fences for cross-XCD visibility (G16).
__device__ __forceinline__ void gbar(unsigned* cnt, unsigned want) {
    __syncthreads();
    if (threadIdx.x == 0) {
        __threadfence();                  // release my writes to device scope
        atomicAdd(cnt, 1u);               // device-scope by default (m20)
        while (__hip_atomic_load(cnt, __ATOMIC_RELAXED,
                                 __HIP_MEMORY_SCOPE_AGENT) < want)
            __builtin_amdgcn_s_sleep(1);
        __threadfence();                  // acquire: invalidate stale cache
    }
    __syncthreads();
}

__global__ void init_kernel(unsigned* mm, float* emd) {
    int t = threadIdx.x;                  // 1024 threads
    if (t < 12) mm[t] = (t & 1) ? 0u : 0xFFFFFFFFu;
    if (t == 12) mm[12] = 0u;             // barrier counter
    emd[t] = 0.f;
}

__global__ __launch_bounds__(256, 4) void fused_kernel(
        const float* __restrict__ ref, const float* __restrict__ tgt,
        float* __restrict__ lab, unsigned* __restrict__ mm,
        float* __restrict__ hr, float* __restrict__ ht,
        float* __restrict__ emdv,
        short* __restrict__ uh, short* __restrict__ ul,
        short* __restrict__ vh, short* __restrict__ vl,
        short* __restrict__ kmh, short* __restrict__ kml,
        short* __restrict__ kch, short* __restrict__ kcl,
        float* __restrict__ out) {
    int w = blockIdx.x, tid = threadIdx.x;
    unsigned* cnt = mm + 12;
    __shared__ unsigned shist[512];
    __shared__ unsigned smin[3], smax[3];
    __shared__ float es[64];

    // ---------------- Phase 0: srgb->oklab + global minmax ----------------
    {
        int img = w >> 7;                       // wgs 0..127 ref, 128..255 tgt
        const float* src = img ? tgt : ref;
        float* dst = lab + img * LAB_STRIDE;
        if (tid < 3) { smin[tid] = 0xFFFFFFFFu; smax[tid] = 0u; }
        __syncthreads();
        float fmn[3] = {3.4e38f, 3.4e38f, 3.4e38f};
        float fmx[3] = {-3.4e38f, -3.4e38f, -3.4e38f};
        #pragma unroll
        for (int k = 0; k < 8; ++k) {
            int px = w * 2048 + k * 256 + tid;
            int local = px & 262143;
            int bi = local >> 16, rem = local & 65535;
            float r = s2lin(src[(bi * 3 + 0) * 65536 + rem]);
            float g = s2lin(src[(bi * 3 + 1) * 65536 + rem]);
            float b = s2lin(src[(bi * 3 + 2) * 65536 + rem]);
            float l0 = fmaxf(0.4122214708f * r + 0.5363325363f * g + 0.0514459929f * b, 0.f);
            float l1 = fmaxf(0.2119034982f * r + 0.6806995451f * g + 0.1073969566f * b, 0.f);
            float l2 = fmaxf(0.0883024619f * r + 0.2817188376f * g + 0.6299787005f * b, 0.f);
            float g0 = (l0 > 0.f) ? cbrt_fast(l0) : 0.f;
            float g1 = (l1 > 0.f) ? cbrt_fast(l1) : 0.f;
            float g2 = (l2 > 0.f) ? cbrt_fast(l2) : 0.f;
            float L  = 0.2104542553f * g0 + 0.793617785f  * g1 - 0.0040720468f * g2;
            float A  = 1.9779984951f * g0 - 2.428592205f  * g1 + 0.4505937099f * g2;
            float Bv = 0.0259040371f * g0 + 0.7827717662f * g1 - 0.808675766f  * g2;
            dst[(bi * 3 + 0) * 65536 + rem] = L;
            dst[(bi * 3 + 1) * 65536 + rem] = A;
            dst[(bi * 3 + 2) * 65536 + rem] = Bv;
            fmn[0] = fminf(fmn[0], L);  fmx[0] = fmaxf(fmx[0], L);
            fmn[1] = fminf(fmn[1], A);  fmx[1] = fmaxf(fmx[1], A);
            fmn[2] = fminf(fmn[2], Bv); fmx[2] = fmaxf(fmx[2], Bv);
        }
        for (int c = 0; c < 3; ++c) {
            atomicMin(&smin[c], enc_f(fmn[c]));
            atomicMax(&smax[c], enc_f(fmx[c]));
        }
        __syncthreads();
        if (tid < 3) {
            atomicMin(&mm[img * 6 + tid * 2 + 0], smin[tid]);
            atomicMax(&mm[img * 6 + tid * 2 + 1], smax[tid]);
        }
    }
    gbar(cnt, NWG * 1);

    // ------------- Phase 1: pack K (frag order) + hist + u-init -------------
    {
        float lo0[3], hi0[3], lo1[3], hi1[3];
        lohi_img(mm, 0, lo0, hi0);
        lohi_img(mm, 1, lo1, hi1);
        float cen[3][8];
        for (int c = 0; c < 3; ++c)
            for (int k = 0; k < 8; ++k) {
                float t = (k + 0.5f) * 0.125f;
                cen[c][k] = 0.5f * ((lo0[c] + (hi0[c] - lo0[c]) * t)
                                  + (lo1[c] + (hi1[c] - lo1[c]) * t));
            }
        // pack: 65536 threads x 4 entries = 262144 entries
        int g = w * 256 + tid;
        int half = g & 1, lane = (g >> 1) & 63, kc = (g >> 7) & 15, jt = g >> 11;
        int n = jt * 16 + (lane & 15);
        int kb = kc * 32 + ((lane >> 4) << 3) + half * 4;
        float n0 = cen[0][n >> 6], n1 = cen[1][(n >> 3) & 7], n2 = cen[2][n & 7];
        short4_t vmh, vml, vch, vcl;
        #pragma unroll
        for (int r = 0; r < 4; ++r) {
            int k = kb + r;
            float d0 = cen[0][k >> 6] - n0;
            float d1 = cen[1][(k >> 3) & 7] - n1;
            float d2 = cen[2][k & 7] - n2;
            float dd = d0 * d0 + d1 * d1 + d2 * d2;
            float cost = (dd > 0.f) ? __fsqrt_rn(dd) : 0.f;
            float kv = hw_exp2(-cost * 14.426950408889634f);   // exp(-cost/0.1)
            float cv = kv * cost;
            unsigned h = bf16_rne(kv);
            vmh[r] = (short)h;
            vml[r] = (short)bf16_rne(kv - bf16_to_f((unsigned short)h));
            h = bf16_rne(cv);
            vch[r] = (short)h;
            vcl[r] = (short)bf16_rne(cv - bf16_to_f((unsigned short)h));
        }
        int base = ((jt * 16 + kc) * 64 + lane) * 8 + half * 4;
        *(short4_t*)(kmh + base) = vmh;
        *(short4_t*)(kml + base) = vml;
        *(short4_t*)(kch + base) = vch;
        *(short4_t*)(kcl + base) = vcl;
        // u-init = ones
        #pragma unroll
        for (int k = 0; k < 8; ++k) {
            int i = w * 2048 + k * 256 + tid;
            uh[i] = (short)0x3F80; ul[i] = 0;
        }
        // hist: wg handles 8 patch-imgs
        int img = w >> 7;
        float cenI[3][8];
        {
            const float* lo = img ? lo1 : lo0;
            const float* hi = img ? hi1 : hi0;
            for (int c = 0; c < 3; ++c)
                for (int k = 0; k < 8; ++k)
                    cenI[c][k] = lo[c] + (hi[c] - lo[c]) * ((k + 0.5f) * 0.125f);
        }
        const float* lb = lab + img * LAB_STRIDE;
        for (int s = 0; s < 8; ++s) {
            int p = (w * 8 + s) & 1023;
            __syncthreads();
            shist[tid] = 0u; shist[tid + 256] = 0u;
            __syncthreads();
            int b = p >> 8, phh = (p >> 4) & 15, pw = p & 15;
            int y = tid >> 4, x = tid & 15;
            int rem = (phh * 16 + y) * 256 + (pw * 16 + x);
            int kidx[3];
            for (int c = 0; c < 3; ++c) {
                float vv = lb[(b * 3 + c) * 65536 + rem];
                int best = 0; float bd = 3.4e38f;
                for (int k = 0; k < 8; ++k) {
                    float d = vv - cenI[c][k];
                    float ds = d * d;
                    if (ds < bd) { bd = ds; best = k; }
                }
                kidx[c] = best;
            }
            atomicAdd(&shist[kidx[0] * 64 + kidx[1] * 8 + kidx[2]], 1u);
            __syncthreads();
            float* dst = img ? ht : hr;
            dst[p * 512 + tid]       = (float)shist[tid]       * (1.f / 256.f);
            dst[p * 512 + tid + 256] = (float)shist[tid + 256] * (1.f / 256.f);
        }
    }
    gbar(cnt, NWG * 2);

    // ------------- Phases 2..41: 40 Sinkhorn half-iterations -------------
    int wave = tid >> 6, lane = tid & 63;
    int pt = w >> 4, jt = w & 15;                 // 16 p-groups x 16 j-groups
    int mbase = pt * 64 + wave * 16;
    int arow_base = (mbase + (lane & 15)) * 512 + ((lane >> 4) << 3);
    for (int h = 0; h < 40; ++h) {
        const short* sh = (h & 1) ? vh : uh;
        const short* sl = (h & 1) ? vl : ul;
        short* dh = (h & 1) ? uh : vh;
        short* dl = (h & 1) ? ul : vl;
        const float* hist = (h & 1) ? hr : ht;
        floatx4 acc0 = {0.f, 0.f, 0.f, 0.f}, acc1 = {0.f, 0.f, 0.f, 0.f};
        #pragma unroll 4
        for (int kc = 0; kc < 16; ++kc) {
            int aoff = arow_base + kc * 32;
            short8 ah = *(const short8*)(sh + aoff);
            short8 al = *(const short8*)(sl + aoff);
            int b0 = (((jt * 2 + 0) * 16 + kc) * 64 + lane) * 8;
            int b1 = (((jt * 2 + 1) * 16 + kc) * 64 + lane) * 8;
            short8 bh0 = *(const short8*)(kmh + b0);
            short8 bl0 = *(const short8*)(kml + b0);
            short8 bh1 = *(const short8*)(kmh + b1);
            short8 bl1 = *(const short8*)(kml + b1);
            acc0 = __builtin_amdgcn_mfma_f32_16x16x32_bf16(ah, bh0, acc0, 0, 0, 0);
            acc1 = __builtin_amdgcn_mfma_f32_16x16x32_bf16(ah, bh1, acc1, 0, 0, 0);
            acc0 = __builtin_amdgcn_mfma_f32_16x16x32_bf16(ah, bl0, acc0, 0, 0, 0);
            acc1 = __builtin_amdgcn_mfma_f32_16x16x32_bf16(ah, bl1, acc1, 0, 0, 0);
            acc0 = __builtin_amdgcn_mfma_f32_16x16x32_bf16(al, bh0, acc0, 0, 0, 0);
            acc1 = __builtin_amdgcn_mfma_f32_16x16x32_bf16(al, bh1, acc1, 0, 0, 0);
        }
        int pr = mbase + ((lane >> 4) << 2);
        int jc0 = jt * 32 + (lane & 15);
        int jc1 = jc0 + 16;
        #pragma unroll
        for (int r = 0; r < 4; ++r) {
            int i0 = (pr + r) * 512 + jc0;
            float d = hist[i0] / (acc0[r] + 1e-6f);
            unsigned hb = bf16_rne(d);
            dh[i0] = (short)hb;
            dl[i0] = (short)bf16_rne(d - bf16_to_f((unsigned short)hb));
            int i1 = (pr + r) * 512 + jc1;
            d = hist[i1] / (acc1[r] + 1e-6f);
            hb = bf16_rne(d);
            dh[i1] = (short)hb;
            dl[i1] = (short)bf16_rne(d - bf16_to_f((unsigned short)hb));
        }
        gbar(cnt, NWG * (3 + h));
    }

    // ------------- Phase 42: EMD = u^T (K.c) v, reduce per patch -------------
    {
        if (tid < 64) es[tid] = 0.f;
        floatx4 acc0 = {0.f, 0.f, 0.f, 0.f}, acc1 = {0.f, 0.f, 0.f, 0.f};
        #pragma unroll 4
        for (int kc = 0; kc < 16; ++kc) {
            int aoff = arow_base + kc * 32;
            short8 ah = *(const short8*)(uh + aoff);
            short8 al = *(const short8*)(ul + aoff);
            int b0 = (((jt * 2 + 0) * 16 + kc) * 64 + lane) * 8;
            int b1 = (((jt * 2 + 1) * 16 + kc) * 64 + lane) * 8;
            short8 bh0 = *(const short8*)(kch + b0);
            short8 bl0 = *(const short8*)(kcl + b0);
            short8 bh1 = *(const short8*)(kch + b1);
            short8 bl1 = *(const short8*)(kcl + b1);
            acc0 = __builtin_amdgcn_mfma_f32_16x16x32_bf16(ah, bh0, acc0, 0, 0, 0);
            acc1 = __builtin_amdgcn_mfma_f32_16x16x32_bf16(ah, bh1, acc1, 0, 0, 0);
            acc0 = __builtin_amdgcn_mfma_f32_16x16x32_bf16(ah, bl0, acc0, 0, 0, 0);
            acc1 = __builtin_amdgcn_mfma_f32_16x16x32_bf16(ah, bl1, acc1, 0, 0, 0);
            acc0 = __builtin_amdgcn_mfma_f32_16x16x32_bf16(al, bh0, acc0, 0, 0, 0);
            acc1 = __builtin_amdgcn_mfma_f32_16x16x32_bf16(al, bh1, acc1, 0, 0, 0);
        }
        __syncthreads();
        int pr = mbase + ((lane >> 4) << 2);
        int jc0 = jt * 32 + (lane & 15);
        int jc1 = jc0 + 16;
        #pragma unroll
        for (int r = 0; r < 4; ++r) {
            int i0 = (pr + r) * 512 + jc0;
            int i1 = (pr + r) * 512 + jc1;
            float v0 = bf16_to_f((unsigned short)vh[i0]) + bf16_to_f((unsigned short)vl[i0]);
            float v1 = bf16_to_f((unsigned short)vh[i1]) + bf16_to_f((unsigned short)vl[i1]);
            atomicAdd(&es[pr + r - pt * 64], acc0[r] * v0 + acc1[r] * v1);
        }
        __syncthreads();
        if (tid < 64) atomicAdd(&emdv[pt * 64 + tid], es[tid]);
    }
    gbar(cnt, NWG * 43);

    // ------------- Phase 43: bilinear 16x upsample + nan_to_num -------------
    #pragma unroll
    for (int k = 0; k < 4; ++k) {
        int idx = w * 1024 + k * 256 + tid;      // 0..262143
        int b = idx >> 16;
        int rem = idx & 65535;
        int y = rem >> 8, x = rem & 255;
        float sy = (y + 0.5f) * 0.0625f - 0.5f;
        float sx = (x + 0.5f) * 0.0625f - 0.5f;
        float fy0 = floorf(sy), fx0 = floorf(sx);
        float fy = sy - fy0, fx = sx - fx0;
        int y0 = (int)fy0, x0 = (int)fx0;
        int y0c = min(max(y0, 0), 15), y1c = min(max(y0 + 1, 0), 15);
        int x0c = min(max(x0, 0), 15), x1c = min(max(x0 + 1, 0), 15);
        const float* e = emdv + b * 256;
        float v00 = e[y0c * 16 + x0c], v01 = e[y0c * 16 + x1c];
        float v10 = e[y1c * 16 + x0c], v11 = e[y1c * 16 + x1c];
        if (!__builtin_isfinite(v00)) v00 = 0.f;
        if (!__builtin_isfinite(v01)) v01 = 0.f;
        if (!__builtin_isfinite(v10)) v10 = 0.f;
        if (!__builtin_isfinite(v11)) v11 = 0.f;
        out[idx] = (1.f - fy) * ((1.f - fx) * v00 + fx * v01)
                 + fy * ((1.f - fx) * v10 + fx * v11);
    }
}

extern "C" void kernel_launch(void* const* d_in, const int* in_sizes, int n_in,
                              void* d_out, int out_size, void* d_ws, size_t ws_size,
                              hipStream_t stream) {
    const float* ref = (const float*)d_in[0];
    const float* tgt = (const float*)d_in[1];
    float* out = (float*)d_out;

    float* lab = (float*)d_ws;                        // 1572864 f32
    unsigned* mm = (unsigned*)(lab + 2 * LAB_STRIDE); // 16 u32 (12 minmax + cnt)
    float* hr = (float*)(mm + 16);                    // 524288 f32
    float* ht = hr + 524288;                          // 524288 f32
    float* emd = ht + 524288;                         // 1024 f32
    short* uh = (short*)(emd + 1024);                 // 524288 bf16 each
    short* ul = uh + 524288;
    short* vh = ul + 524288;
    short* vl = vh + 524288;
    short* kmh = vl + 524288;                         // 262144 bf16 each
    short* kml = kmh + 262144;
    short* kch = kml + 262144;
    short* kcl = kch + 262144;

    init_kernel<<<1, 1024, 0, stream>>>(mm, emd);
    fused_kernel<<<NWG, 256, 0, stream>>>(ref, tgt, lab, mm, hr, ht, emd,
                                          uh, ul, vh, vl, kmh, kml, kch, kcl,
                                          out);
}

// Round 6
// 294.027 us; speedup vs baseline: 5.7057x; 5.7057x over previous
//
#include <hip/hip_runtime.h>
#include <hip/hip_bf16.h>

// ChromaticTransportEvaluator — round 6.
// R5 post-mortem: device-scope barrier fences invalidate L2 (FETCH 426 MB,
// 38us/barrier). New structure: Sinkhorn is patch-parallel -> run ALL 20
// iterations inside one block (8 patches/block, u/v in LDS, only
// __syncthreads). K stored as SINGLE f16 B-fragments (rel 2^-11), u/v as
// f16 hi/lo (rel 2^-21). Per-CU cost = 41 x 512KB K-stream from L2.
// Also: oklab was global-atomic-serialization-bound (1024 blocks x 6 same-
// address atomics) -> 128 blocks + wave shuffle reduce.
//
// mfma_f32_16x16x32_f16 layouts (shape-determined, dtype-independent):
//   A[m][k]: m = lane&15, k = (lane>>4)*8 + reg
//   B[k][n]: n = lane&15, k = (lane>>4)*8 + reg
//   C/D:     col = lane&15, row = (lane>>4)*4 + reg

#define LAB_STRIDE 786432         // 4*3*256*256 floats per image-set
#define SPITCH 520                // f16 row pitch for LDS u/v buffers

typedef __attribute__((ext_vector_type(8))) _Float16 half8_t;
typedef __attribute__((ext_vector_type(4))) float floatx4;

__device__ __forceinline__ float hw_exp2(float x) { return __builtin_amdgcn_exp2f(x); }
__device__ __forceinline__ float hw_log2(float x) { return __builtin_amdgcn_logf(x); }

__device__ __forceinline__ unsigned enc_f(float f) {
    unsigned u = __float_as_uint(f);
    return (u & 0x80000000u) ? ~u : (u | 0x80000000u);
}
__device__ __forceinline__ float dec_f(unsigned k) {
    unsigned u = (k & 0x80000000u) ? (k ^ 0x80000000u) : ~k;
    return __uint_as_float(u);
}

__device__ __forceinline__ float s2lin(float x) {
    x = fminf(fmaxf(x, 0.f), 1.f);
    return (x <= 0.04045f) ? (x * (1.f / 12.92f))
                           : hw_exp2(2.4f * hw_log2((x + 0.055f) * (1.f / 1.055f)));
}
__device__ __forceinline__ float cbrt_fast(float l) {
    return hw_exp2(0.33333333333f * hw_log2(fmaxf(l, 1e-12f)));
}

__device__ __forceinline__ void lohi_img(const unsigned* mm, int img,
                                         float lo[3], float hi[3]) {
    for (int c = 0; c < 3; ++c) {
        float mn = dec_f(mm[img * 6 + c * 2 + 0]);
        float mx = dec_f(mm[img * 6 + c * 2 + 1]);
        float l = mn - 0.01f, h = mx + 0.01f;
        if (h - l < 1e-4f) { l -= 0.05f; h += 0.05f; }
        lo[c] = l; hi[c] = h;
    }
}

__global__ void init_kernel(unsigned* mm) {
    int t = threadIdx.x;
    if (t < 12) mm[t] = (t & 1) ? 0u : 0xFFFFFFFFu;
}

// 128 blocks x 256 threads x 16 px. img = blk>>6. Wave shuffle-reduce minmax,
// 6 global atomics per block (128 per address total).
__global__ __launch_bounds__(256) void oklab_minmax_kernel(
        const float* __restrict__ ref, const float* __restrict__ tgt,
        float* __restrict__ lab, unsigned* __restrict__ mm) {
    int blk = blockIdx.x, tid = threadIdx.x;
    int img = blk >> 6;
    const float* src = img ? tgt : ref;
    float* dst = lab + img * LAB_STRIDE;

    __shared__ unsigned smin[3], smax[3];
    if (tid < 3) { smin[tid] = 0xFFFFFFFFu; smax[tid] = 0u; }
    __syncthreads();

    float fmn[3] = {3.4e38f, 3.4e38f, 3.4e38f};
    float fmx[3] = {-3.4e38f, -3.4e38f, -3.4e38f};
    int base = (blk & 63) * 4096;
    #pragma unroll 4
    for (int k = 0; k < 16; ++k) {
        int px = base + k * 256 + tid;          // 0..262143
        int bi = px >> 16, rem = px & 65535;
        float r = s2lin(src[(bi * 3 + 0) * 65536 + rem]);
        float g = s2lin(src[(bi * 3 + 1) * 65536 + rem]);
        float b = s2lin(src[(bi * 3 + 2) * 65536 + rem]);
        float l0 = fmaxf(0.4122214708f * r + 0.5363325363f * g + 0.0514459929f * b, 0.f);
        float l1 = fmaxf(0.2119034982f * r + 0.6806995451f * g + 0.1073969566f * b, 0.f);
        float l2 = fmaxf(0.0883024619f * r + 0.2817188376f * g + 0.6299787005f * b, 0.f);
        float g0 = (l0 > 0.f) ? cbrt_fast(l0) : 0.f;
        float g1 = (l1 > 0.f) ? cbrt_fast(l1) : 0.f;
        float g2 = (l2 > 0.f) ? cbrt_fast(l2) : 0.f;
        float L  = 0.2104542553f * g0 + 0.793617785f  * g1 - 0.0040720468f * g2;
        float A  = 1.9779984951f * g0 - 2.428592205f  * g1 + 0.4505937099f * g2;
        float Bv = 0.0259040371f * g0 + 0.7827717662f * g1 - 0.808675766f  * g2;
        dst[(bi * 3 + 0) * 65536 + rem] = L;
        dst[(bi * 3 + 1) * 65536 + rem] = A;
        dst[(bi * 3 + 2) * 65536 + rem] = Bv;
        fmn[0] = fminf(fmn[0], L);  fmx[0] = fmaxf(fmx[0], L);
        fmn[1] = fminf(fmn[1], A);  fmx[1] = fmaxf(fmx[1], A);
        fmn[2] = fminf(fmn[2], Bv); fmx[2] = fmaxf(fmx[2], Bv);
    }
    // wave reduce (64 lanes)
    for (int s = 1; s < 64; s <<= 1) {
        for (int c = 0; c < 3; ++c) {
            fmn[c] = fminf(fmn[c], __shfl_xor(fmn[c], s));
            fmx[c] = fmaxf(fmx[c], __shfl_xor(fmx[c], s));
        }
    }
    if ((tid & 63) == 0) {
        for (int c = 0; c < 3; ++c) {
            atomicMin(&smin[c], enc_f(fmn[c]));
            atomicMax(&smax[c], enc_f(fmx[c]));
        }
    }
    __syncthreads();
    if (tid < 3) {
        atomicMin(&mm[img * 6 + tid * 2 + 0], smin[tid]);
        atomicMax(&mm[img * 6 + tid * 2 + 1], smax[tid]);
    }
}

// 2048 blocks x 256 thr: all blocks do 1 patch histogram; blocks 0..255 also
// pack K (f16, B-frag order, 4 entries/thread).
__global__ __launch_bounds__(256) void pack_hist_kernel(
        const float* __restrict__ lab, const unsigned* __restrict__ mm,
        float* __restrict__ hr, float* __restrict__ ht,
        _Float16* __restrict__ kmf, _Float16* __restrict__ kcf) {
    int blk = blockIdx.x, tid = threadIdx.x;
    float lo0[3], hi0[3], lo1[3], hi1[3];
    lohi_img(mm, 0, lo0, hi0);
    lohi_img(mm, 1, lo1, hi1);

    if (blk < 256) {
        float cen[3][8];
        for (int c = 0; c < 3; ++c)
            for (int k = 0; k < 8; ++k) {
                float t = (k + 0.5f) * 0.125f;
                cen[c][k] = 0.5f * ((lo0[c] + (hi0[c] - lo0[c]) * t)
                                  + (lo1[c] + (hi1[c] - lo1[c]) * t));
            }
        int g = blk * 256 + tid;
        int half = g & 1, lane = (g >> 1) & 63, kc = (g >> 7) & 15, jt = g >> 11;
        int n = jt * 16 + (lane & 15);
        int kb = kc * 32 + ((lane >> 4) << 3) + half * 4;
        float n0 = cen[0][n >> 6], n1 = cen[1][(n >> 3) & 7], n2 = cen[2][n & 7];
        int base = ((jt * 16 + kc) * 64 + lane) * 8 + half * 4;
        #pragma unroll
        for (int r = 0; r < 4; ++r) {
            int k = kb + r;
            float d0 = cen[0][k >> 6] - n0;
            float d1 = cen[1][(k >> 3) & 7] - n1;
            float d2 = cen[2][k & 7] - n2;
            float dd = d0 * d0 + d1 * d1 + d2 * d2;
            float cost = (dd > 0.f) ? __fsqrt_rn(dd) : 0.f;
            float kv = hw_exp2(-cost * 14.426950408889634f);   // exp(-cost/0.1)
            kmf[base + r] = (_Float16)kv;
            kcf[base + r] = (_Float16)(kv * cost);
        }
    }

    // histogram: patch p of image-set img
    int img = blk >> 10;
    int p = blk & 1023;
    float cenI[3][8];
    {
        const float* lo = img ? lo1 : lo0;
        const float* hi = img ? hi1 : hi0;
        for (int c = 0; c < 3; ++c)
            for (int k = 0; k < 8; ++k)
                cenI[c][k] = lo[c] + (hi[c] - lo[c]) * ((k + 0.5f) * 0.125f);
    }
    __shared__ unsigned hcnt[512];
    hcnt[tid] = 0u; hcnt[tid + 256] = 0u;
    __syncthreads();
    int b = p >> 8, ph = (p >> 4) & 15, pw = p & 15;
    int y = tid >> 4, x = tid & 15;
    int rem = (ph * 16 + y) * 256 + (pw * 16 + x);
    const float* lb = lab + img * LAB_STRIDE;
    int kidx[3];
    for (int c = 0; c < 3; ++c) {
        float vv = lb[(b * 3 + c) * 65536 + rem];
        int best = 0; float bd = 3.4e38f;
        for (int k = 0; k < 8; ++k) {
            float d = vv - cenI[c][k];
            float ds = d * d;
            if (ds < bd) { bd = ds; best = k; }
        }
        kidx[c] = best;
    }
    atomicAdd(&hcnt[kidx[0] * 64 + kidx[1] * 8 + kidx[2]], 1u);
    __syncthreads();
    float* dst = img ? ht : hr;
    dst[p * 512 + tid]       = (float)hcnt[tid]       * (1.f / 256.f);
    dst[p * 512 + tid + 256] = (float)hcnt[tid + 256] * (1.f / 256.f);
}

// The big one: 128 blocks x 512 threads (8 waves). Block owns 8 patches,
// runs all 40 Sinkhorn half-iterations + EMD locally. u/v in LDS (f16
// hi/lo), K streamed from L2 as f16 B-frags. Wave w owns j-cols [w*64,w*64+64).
__global__ __launch_bounds__(512, 2) void sinkhorn_kernel(
        const float* __restrict__ hr, const float* __restrict__ ht,
        const _Float16* __restrict__ kmf, const _Float16* __restrict__ kcf,
        float* __restrict__ emd) {
    __shared__ __align__(16) _Float16 Uh[16 * SPITCH], Ul[16 * SPITCH];
    __shared__ __align__(16) _Float16 Vh[16 * SPITCH], Vl[16 * SPITCH];
    __shared__ float hrs[8 * 512], hts[8 * 512];
    __shared__ float ebuf[8];
    int tid = threadIdx.x;
    int wave = tid >> 6, lane = tid & 63;
    int pbase = blockIdx.x * 8;

    for (int i = tid; i < 4096; i += 512) {
        hrs[i] = hr[pbase * 512 + i];
        hts[i] = ht[pbase * 512 + i];
    }
    for (int i = tid; i < 16 * SPITCH; i += 512) {
        int row = i / SPITCH;
        Uh[i] = (row < 8) ? (_Float16)1.0f : (_Float16)0.0f;
        Ul[i] = (_Float16)0.0f;
        Vh[i] = (_Float16)0.0f;
        Vl[i] = (_Float16)0.0f;
    }
    if (tid < 8) ebuf[tid] = 0.f;
    __syncthreads();

    int mrow = lane & 15;          // A row
    int kgrp = (lane >> 4) << 3;   // A k-offset
    int jt0 = wave * 4;
    int colc = lane & 15;          // C col
    int rquad = lane >> 4;         // C rows rquad*4..+3

    for (int h = 0; h < 40; ++h) {
        const _Float16* sh = (h & 1) ? Vh : Uh;
        const _Float16* sl = (h & 1) ? Vl : Ul;
        _Float16* dh = (h & 1) ? Uh : Vh;
        _Float16* dl = (h & 1) ? Ul : Vl;
        const float* hs = (h & 1) ? hrs : hts;
        floatx4 A[4] = {{0,0,0,0},{0,0,0,0},{0,0,0,0},{0,0,0,0}};
        #pragma unroll 4
        for (int kc = 0; kc < 16; ++kc) {
            half8_t ah = *(const half8_t*)&sh[mrow * SPITCH + kc * 32 + kgrp];
            half8_t al = *(const half8_t*)&sl[mrow * SPITCH + kc * 32 + kgrp];
            const _Float16* bb = kmf + (kc * 64 + lane) * 8;
            #pragma unroll
            for (int q = 0; q < 4; ++q) {
                half8_t b = *(const half8_t*)(bb + (jt0 + q) * 8192);
                A[q] = __builtin_amdgcn_mfma_f32_16x16x32_f16(ah, b, A[q], 0, 0, 0);
                A[q] = __builtin_amdgcn_mfma_f32_16x16x32_f16(al, b, A[q], 0, 0, 0);
            }
        }
        if (rquad < 2) {
            #pragma unroll
            for (int q = 0; q < 4; ++q) {
                int col = (jt0 + q) * 16 + colc;
                #pragma unroll
                for (int r = 0; r < 4; ++r) {
                    int row = rquad * 4 + r;
                    float d = hs[row * 512 + col] / (A[q][r] + 1e-6f);
                    d = fminf(d, 60000.f);
                    _Float16 hi16 = (_Float16)d;
                    dh[row * SPITCH + col] = hi16;
                    dl[row * SPITCH + col] = (_Float16)(d - (float)hi16);
                }
            }
        }
        __syncthreads();
    }

    // EMD: acc = u @ KC (per j-slice), dot with v, reduce per patch.
    {
        floatx4 A[4] = {{0,0,0,0},{0,0,0,0},{0,0,0,0},{0,0,0,0}};
        #pragma unroll 4
        for (int kc = 0; kc < 16; ++kc) {
            half8_t ah = *(const half8_t*)&Uh[mrow * SPITCH + kc * 32 + kgrp];
            half8_t al = *(const half8_t*)&Ul[mrow * SPITCH + kc * 32 + kgrp];
            const _Float16* bb = kcf + (kc * 64 + lane) * 8;
            #pragma unroll
            for (int q = 0; q < 4; ++q) {
                half8_t b = *(const half8_t*)(bb + (jt0 + q) * 8192);
                A[q] = __builtin_amdgcn_mfma_f32_16x16x32_f16(ah, b, A[q], 0, 0, 0);
                A[q] = __builtin_amdgcn_mfma_f32_16x16x32_f16(al, b, A[q], 0, 0, 0);
            }
        }
        float pe[4] = {0.f, 0.f, 0.f, 0.f};
        if (rquad < 2) {
            #pragma unroll
            for (int q = 0; q < 4; ++q) {
                int col = (jt0 + q) * 16 + colc;
                #pragma unroll
                for (int r = 0; r < 4; ++r) {
                    int row = rquad * 4 + r;
                    float vv = (float)Vh[row * SPITCH + col]
                             + (float)Vl[row * SPITCH + col];
                    pe[r] += A[q][r] * vv;
                }
            }
        }
        for (int s = 1; s < 16; s <<= 1) {
            #pragma unroll
            for (int r = 0; r < 4; ++r) pe[r] += __shfl_xor(pe[r], s);
        }
        if (colc == 0 && rquad < 2) {
            #pragma unroll
            for (int r = 0; r < 4; ++r)
                atomicAdd(&ebuf[rquad * 4 + r], pe[r]);
        }
        __syncthreads();
        if (tid < 8) {
            float e = ebuf[tid];
            if (!__builtin_isfinite(e)) e = 0.f;
            emd[pbase + tid] = e;
        }
    }
}

// (4,1,16,16) -> (4,1,256,256), half-pixel bilinear, edge clamp, nan_to_num
__global__ __launch_bounds__(256) void upsample_kernel(
        const float* __restrict__ emd, float* __restrict__ out) {
    #pragma unroll
    for (int k = 0; k < 4; ++k) {
        int idx = blockIdx.x * 1024 + k * 256 + threadIdx.x;   // 0..262143
        int b = idx >> 16;
        int rem = idx & 65535;
        int y = rem >> 8, x = rem & 255;
        float sy = (y + 0.5f) * 0.0625f - 0.5f;
        float sx = (x + 0.5f) * 0.0625f - 0.5f;
        float fy0 = floorf(sy), fx0 = floorf(sx);
        float fy = sy - fy0, fx = sx - fx0;
        int y0 = (int)fy0, x0 = (int)fx0;
        int y0c = min(max(y0, 0), 15), y1c = min(max(y0 + 1, 0), 15);
        int x0c = min(max(x0, 0), 15), x1c = min(max(x0 + 1, 0), 15);
        const float* e = emd + b * 256;
        float v00 = e[y0c * 16 + x0c], v01 = e[y0c * 16 + x1c];
        float v10 = e[y1c * 16 + x0c], v11 = e[y1c * 16 + x1c];
        out[idx] = (1.f - fy) * ((1.f - fx) * v00 + fx * v01)
                 + fy * ((1.f - fx) * v10 + fx * v11);
    }
}

extern "C" void kernel_launch(void* const* d_in, const int* in_sizes, int n_in,
                              void* d_out, int out_size, void* d_ws, size_t ws_size,
                              hipStream_t stream) {
    const float* ref = (const float*)d_in[0];
    const float* tgt = (const float*)d_in[1];
    float* out = (float*)d_out;

    float* lab = (float*)d_ws;                        // 1572864 f32
    unsigned* mm = (unsigned*)(lab + 2 * LAB_STRIDE); // 16 u32
    float* hr = (float*)(mm + 16);                    // 524288 f32
    float* ht = hr + 524288;                          // 524288 f32
    float* emd = ht + 524288;                         // 1024 f32
    _Float16* kmf = (_Float16*)(emd + 1024);          // 262144 f16
    _Float16* kcf = kmf + 262144;                     // 262144 f16

    init_kernel<<<1, 64, 0, stream>>>(mm);
    oklab_minmax_kernel<<<128, 256, 0, stream>>>(ref, tgt, lab, mm);
    pack_hist_kernel<<<2048, 256, 0, stream>>>(lab, mm, hr, ht, kmf, kcf);
    sinkhorn_kernel<<<128, 512, 0, stream>>>(hr, ht, kmf, kcf, emd);
    upsample_kernel<<<256, 256, 0, stream>>>(emd, out);
}

// Round 7
// 220.168 us; speedup vs baseline: 7.6198x; 1.3355x over previous
//
#include <hip/hip_runtime.h>
#include <hip/hip_bf16.h>

// ChromaticTransportEvaluator — round 7.
// R6 post-mortem: sinkhorn is L2-port-bound on the K stream (96 GB/s/CU ~ 70%
// of per-CU port; 41 passes x 512 KB). Cuts this round:
//  * u/v single f16 (2^-11/iter, non-compounding) -> half MFMA + A-reads.
//  * K kc-chunks 0..2 (96 KB) cached in LDS -> L2 stream 512->416 KB/pass.
//  * hist as f16 in LDS (counts/256 are exact in f16).
//  * init_kernel dropped (per-block minmax + butterfly reduce in consumers).
// K fragment layout changed to [kc][jt][lane][8] so the cached region is one
// contiguous 96 KB prefix.
//
// mfma_f32_16x16x32_f16 layouts (shape-determined):
//   A[m][k]: m = lane&15, k = (lane>>4)*8 + reg
//   B[k][n]: n = lane&15, k = (lane>>4)*8 + reg
//   C/D:     col = lane&15, row = (lane>>4)*4 + reg

#define LAB_STRIDE 786432         // 4*3*256*256 floats per image-set
#define SP 520                    // f16 pitch for LDS u/v (multiple of 8)

typedef __attribute__((ext_vector_type(8))) _Float16 half8_t;
typedef __attribute__((ext_vector_type(4))) _Float16 half4_t;
typedef __attribute__((ext_vector_type(4))) float floatx4;

__device__ __forceinline__ float hw_exp2(float x) { return __builtin_amdgcn_exp2f(x); }
__device__ __forceinline__ float hw_log2(float x) { return __builtin_amdgcn_logf(x); }

__device__ __forceinline__ unsigned enc_f(float f) {
    unsigned u = __float_as_uint(f);
    return (u & 0x80000000u) ? ~u : (u | 0x80000000u);
}
__device__ __forceinline__ float dec_f(unsigned k) {
    unsigned u = (k & 0x80000000u) ? (k ^ 0x80000000u) : ~k;
    return __uint_as_float(u);
}

__device__ __forceinline__ float s2lin(float x) {
    x = fminf(fmaxf(x, 0.f), 1.f);
    return (x <= 0.04045f) ? (x * (1.f / 12.92f))
                           : hw_exp2(2.4f * hw_log2((x + 0.055f) * (1.f / 1.055f)));
}
__device__ __forceinline__ float cbrt_fast(float l) {
    return hw_exp2(0.33333333333f * hw_log2(fmaxf(l, 1e-12f)));
}

// Reduce per-block minmax (written by oklab) into lo/hi for image `img`.
// 128 producer blocks per image; butterfly over the wave (every lane ends
// with the result).
__device__ __forceinline__ void compute_lohi(
        const float* __restrict__ bmn, const float* __restrict__ bmx,
        int img, float lo[3], float hi[3]) {
    int lane = threadIdx.x & 63;
    for (int c = 0; c < 3; ++c) {
        float mn = 3.4e38f, mx = -3.4e38f;
        for (int i = lane; i < 128; i += 64) {
            mn = fminf(mn, bmn[(img * 128 + i) * 3 + c]);
            mx = fmaxf(mx, bmx[(img * 128 + i) * 3 + c]);
        }
        for (int s = 1; s < 64; s <<= 1) {
            mn = fminf(mn, __shfl_xor(mn, s));
            mx = fmaxf(mx, __shfl_xor(mx, s));
        }
        float l = mn - 0.01f, h = mx + 0.01f;
        if (h - l < 1e-4f) { l -= 0.05f; h += 0.05f; }
        lo[c] = l; hi[c] = h;
    }
}

// 256 blocks x 256 threads x 8 px. img = blk>>7. Per-block minmax -> plain
// stores (no global atomics, no init dependency).
__global__ __launch_bounds__(256) void oklab_minmax_kernel(
        const float* __restrict__ ref, const float* __restrict__ tgt,
        float* __restrict__ lab, float* __restrict__ bmn, float* __restrict__ bmx) {
    int blk = blockIdx.x, tid = threadIdx.x;
    int img = blk >> 7;
    const float* src = img ? tgt : ref;
    float* dst = lab + img * LAB_STRIDE;

    __shared__ unsigned smin[3], smax[3];
    if (tid < 3) { smin[tid] = 0xFFFFFFFFu; smax[tid] = 0u; }
    __syncthreads();

    float fmn[3] = {3.4e38f, 3.4e38f, 3.4e38f};
    float fmx[3] = {-3.4e38f, -3.4e38f, -3.4e38f};
    int base = (blk & 127) * 2048;
    #pragma unroll
    for (int k = 0; k < 8; ++k) {
        int px = base + k * 256 + tid;          // 0..262143
        int bi = px >> 16, rem = px & 65535;
        float r = s2lin(src[(bi * 3 + 0) * 65536 + rem]);
        float g = s2lin(src[(bi * 3 + 1) * 65536 + rem]);
        float b = s2lin(src[(bi * 3 + 2) * 65536 + rem]);
        float l0 = fmaxf(0.4122214708f * r + 0.5363325363f * g + 0.0514459929f * b, 0.f);
        float l1 = fmaxf(0.2119034982f * r + 0.6806995451f * g + 0.1073969566f * b, 0.f);
        float l2 = fmaxf(0.0883024619f * r + 0.2817188376f * g + 0.6299787005f * b, 0.f);
        float g0 = (l0 > 0.f) ? cbrt_fast(l0) : 0.f;
        float g1 = (l1 > 0.f) ? cbrt_fast(l1) : 0.f;
        float g2 = (l2 > 0.f) ? cbrt_fast(l2) : 0.f;
        float L  = 0.2104542553f * g0 + 0.793617785f  * g1 - 0.0040720468f * g2;
        float A  = 1.9779984951f * g0 - 2.428592205f  * g1 + 0.4505937099f * g2;
        float Bv = 0.0259040371f * g0 + 0.7827717662f * g1 - 0.808675766f  * g2;
        dst[(bi * 3 + 0) * 65536 + rem] = L;
        dst[(bi * 3 + 1) * 65536 + rem] = A;
        dst[(bi * 3 + 2) * 65536 + rem] = Bv;
        fmn[0] = fminf(fmn[0], L);  fmx[0] = fmaxf(fmx[0], L);
        fmn[1] = fminf(fmn[1], A);  fmx[1] = fmaxf(fmx[1], A);
        fmn[2] = fminf(fmn[2], Bv); fmx[2] = fmaxf(fmx[2], Bv);
    }
    for (int s = 1; s < 64; s <<= 1) {
        for (int c = 0; c < 3; ++c) {
            fmn[c] = fminf(fmn[c], __shfl_xor(fmn[c], s));
            fmx[c] = fmaxf(fmx[c], __shfl_xor(fmx[c], s));
        }
    }
    if ((tid & 63) == 0) {
        for (int c = 0; c < 3; ++c) {
            atomicMin(&smin[c], enc_f(fmn[c]));
            atomicMax(&smax[c], enc_f(fmx[c]));
        }
    }
    __syncthreads();
    if (tid < 3) {
        bmn[blk * 3 + tid] = dec_f(smin[tid]);
        bmx[blk * 3 + tid] = dec_f(smax[tid]);
    }
}

// 2048 blocks x 256 thr: every block does 1 patch histogram; blocks 0..255
// also pack K as f16 B-fragments in [kc][jt][lane][8] order.
__global__ __launch_bounds__(256) void pack_hist_kernel(
        const float* __restrict__ lab,
        const float* __restrict__ bmn, const float* __restrict__ bmx,
        float* __restrict__ hr, float* __restrict__ ht,
        _Float16* __restrict__ kmf, _Float16* __restrict__ kcf) {
    int blk = blockIdx.x, tid = threadIdx.x;
    float lo0[3], hi0[3], lo1[3], hi1[3];
    compute_lohi(bmn, bmx, 0, lo0, hi0);
    compute_lohi(bmn, bmx, 1, lo1, hi1);

    if (blk < 256) {
        float cen[3][8];
        for (int c = 0; c < 3; ++c)
            for (int k = 0; k < 8; ++k) {
                float t = (k + 0.5f) * 0.125f;
                cen[c][k] = 0.5f * ((lo0[c] + (hi0[c] - lo0[c]) * t)
                                  + (lo1[c] + (hi1[c] - lo1[c]) * t));
            }
        int g = blk * 256 + tid;
        int half = g & 1, lane = (g >> 1) & 63, kc = (g >> 7) & 15, jt = g >> 11;
        int n = jt * 16 + (lane & 15);
        int kb = kc * 32 + ((lane >> 4) << 3) + half * 4;
        float n0 = cen[0][n >> 6], n1 = cen[1][(n >> 3) & 7], n2 = cen[2][n & 7];
        half4_t vm, vc;
        #pragma unroll
        for (int r = 0; r < 4; ++r) {
            int k = kb + r;
            float d0 = cen[0][k >> 6] - n0;
            float d1 = cen[1][(k >> 3) & 7] - n1;
            float d2 = cen[2][k & 7] - n2;
            float dd = d0 * d0 + d1 * d1 + d2 * d2;
            float cost = (dd > 0.f) ? __fsqrt_rn(dd) : 0.f;
            float kv = hw_exp2(-cost * 14.426950408889634f);   // exp(-cost/0.1)
            vm[r] = (_Float16)kv;
            vc[r] = (_Float16)(kv * cost);
        }
        int base = ((kc * 32 + jt) * 64 + lane) * 8 + half * 4;
        *(half4_t*)(kmf + base) = vm;
        *(half4_t*)(kcf + base) = vc;
    }

    // histogram: patch p of image-set img
    int img = blk >> 10;
    int p = blk & 1023;
    float cenI[3][8];
    {
        const float* lo = img ? lo1 : lo0;
        const float* hi = img ? hi1 : hi0;
        for (int c = 0; c < 3; ++c)
            for (int k = 0; k < 8; ++k)
                cenI[c][k] = lo[c] + (hi[c] - lo[c]) * ((k + 0.5f) * 0.125f);
    }
    __shared__ unsigned hcnt[512];
    hcnt[tid] = 0u; hcnt[tid + 256] = 0u;
    __syncthreads();
    int b = p >> 8, ph = (p >> 4) & 15, pw = p & 15;
    int y = tid >> 4, x = tid & 15;
    int rem = (ph * 16 + y) * 256 + (pw * 16 + x);
    const float* lb = lab + img * LAB_STRIDE;
    int kidx[3];
    for (int c = 0; c < 3; ++c) {
        float vv = lb[(b * 3 + c) * 65536 + rem];
        int best = 0; float bd = 3.4e38f;
        for (int k = 0; k < 8; ++k) {
            float d = vv - cenI[c][k];
            float ds = d * d;
            if (ds < bd) { bd = ds; best = k; }
        }
        kidx[c] = best;
    }
    atomicAdd(&hcnt[kidx[0] * 64 + kidx[1] * 8 + kidx[2]], 1u);
    __syncthreads();
    float* dst = img ? ht : hr;
    dst[p * 512 + tid]       = (float)hcnt[tid]       * (1.f / 256.f);
    dst[p * 512 + tid + 256] = (float)hcnt[tid + 256] * (1.f / 256.f);
}

// 128 blocks x 512 threads (8 waves). Block owns 8 patches, runs all 40
// half-iterations + EMD locally. u/v single f16 in LDS; K kc<3 cached in LDS
// (96 KB), kc 3..15 streamed from L2. Wave w owns j-cols [w*64, w*64+64).
__global__ __launch_bounds__(512, 2) void sinkhorn_kernel(
        const float* __restrict__ hr, const float* __restrict__ ht,
        const _Float16* __restrict__ kmf, const _Float16* __restrict__ kcf,
        float* __restrict__ emd) {
    __shared__ __align__(16) _Float16 U[8 * SP], V[8 * SP];
    __shared__ __align__(16) _Float16 hrs[4096], hts[4096];
    __shared__ __align__(16) _Float16 Kc3[49152];   // kc 0..2 fragments, 96 KB
    __shared__ float ebuf[8];
    int tid = threadIdx.x;
    int wave = tid >> 6, lane = tid & 63;
    int pbase = blockIdx.x * 8;

    for (int i = tid; i < 4096; i += 512) {
        hrs[i] = (_Float16)hr[pbase * 512 + i];
        hts[i] = (_Float16)ht[pbase * 512 + i];
    }
    for (int i = tid; i < 8 * SP; i += 512) U[i] = (_Float16)1.0f;
    for (int i = tid; i < 6144; i += 512)
        *(half8_t*)(Kc3 + i * 8) = *(const half8_t*)(kmf + i * 8);
    if (tid < 8) ebuf[tid] = 0.f;
    __syncthreads();

    int mrow = lane & 15;          // A row (patch)
    int kgrp = (lane >> 4) << 3;   // A k-offset
    int jt0 = wave * 4;            // first of 4 j-tiles for this wave
    int rq = lane >> 4;            // C row-quad
    int colc = lane & 15;          // C col

    for (int h = 0; h < 40; ++h) {
        const _Float16* S = (h & 1) ? V : U;
        _Float16* D = (h & 1) ? U : V;
        const _Float16* hs = (h & 1) ? hrs : hts;
        floatx4 acc[4] = {{0,0,0,0},{0,0,0,0},{0,0,0,0},{0,0,0,0}};
        #pragma unroll
        for (int kc = 0; kc < 3; ++kc) {       // LDS-cached chunks
            half8_t a = *(const half8_t*)&S[mrow * SP + kc * 32 + kgrp];
            #pragma unroll
            for (int q = 0; q < 4; ++q) {
                half8_t b = *(const half8_t*)&Kc3[((kc * 32 + jt0 + q) * 64 + lane) * 8];
                acc[q] = __builtin_amdgcn_mfma_f32_16x16x32_f16(a, b, acc[q], 0, 0, 0);
            }
        }
        #pragma unroll
        for (int kc = 3; kc < 16; ++kc) {      // L2-streamed chunks
            half8_t a = *(const half8_t*)&S[mrow * SP + kc * 32 + kgrp];
            const _Float16* bb = kmf + ((kc * 32 + jt0) * 64 + lane) * 8;
            #pragma unroll
            for (int q = 0; q < 4; ++q) {
                half8_t b = *(const half8_t*)(bb + q * 512);
                acc[q] = __builtin_amdgcn_mfma_f32_16x16x32_f16(a, b, acc[q], 0, 0, 0);
            }
        }
        if (rq < 2) {
            #pragma unroll
            for (int q = 0; q < 4; ++q) {
                int col = (jt0 + q) * 16 + colc;
                #pragma unroll
                for (int r = 0; r < 4; ++r) {
                    int row = rq * 4 + r;
                    float d = (float)hs[row * 512 + col] / (acc[q][r] + 1e-6f);
                    D[row * SP + col] = (_Float16)fminf(d, 60000.f);
                }
            }
        }
        __syncthreads();
    }

    // EMD: acc = u @ Kc (f16, full L2 stream once), dot with v, reduce.
    {
        floatx4 acc[4] = {{0,0,0,0},{0,0,0,0},{0,0,0,0},{0,0,0,0}};
        #pragma unroll
        for (int kc = 0; kc < 16; ++kc) {
            half8_t a = *(const half8_t*)&U[mrow * SP + kc * 32 + kgrp];
            const _Float16* bb = kcf + ((kc * 32 + jt0) * 64 + lane) * 8;
            #pragma unroll
            for (int q = 0; q < 4; ++q) {
                half8_t b = *(const half8_t*)(bb + q * 512);
                acc[q] = __builtin_amdgcn_mfma_f32_16x16x32_f16(a, b, acc[q], 0, 0, 0);
            }
        }
        float pe[4] = {0.f, 0.f, 0.f, 0.f};
        if (rq < 2) {
            #pragma unroll
            for (int q = 0; q < 4; ++q) {
                int col = (jt0 + q) * 16 + colc;
                #pragma unroll
                for (int r = 0; r < 4; ++r)
                    pe[r] += acc[q][r] * (float)V[(rq * 4 + r) * SP + col];
            }
        }
        for (int s = 1; s < 16; s <<= 1) {
            #pragma unroll
            for (int r = 0; r < 4; ++r) pe[r] += __shfl_xor(pe[r], s);
        }
        if (colc == 0 && rq < 2) {
            #pragma unroll
            for (int r = 0; r < 4; ++r)
                atomicAdd(&ebuf[rq * 4 + r], pe[r]);
        }
        __syncthreads();
        if (tid < 8) {
            float e = ebuf[tid];
            emd[pbase + tid] = __builtin_isfinite(e) ? e : 0.f;
        }
    }
}

// (4,1,16,16) -> (4,1,256,256), half-pixel bilinear, edge clamp
__global__ __launch_bounds__(256) void upsample_kernel(
        const float* __restrict__ emd, float* __restrict__ out) {
    #pragma unroll
    for (int k = 0; k < 4; ++k) {
        int idx = blockIdx.x * 1024 + k * 256 + threadIdx.x;   // 0..262143
        int b = idx >> 16;
        int rem = idx & 65535;
        int y = rem >> 8, x = rem & 255;
        float sy = (y + 0.5f) * 0.0625f - 0.5f;
        float sx = (x + 0.5f) * 0.0625f - 0.5f;
        float fy0 = floorf(sy), fx0 = floorf(sx);
        float fy = sy - fy0, fx = sx - fx0;
        int y0 = (int)fy0, x0 = (int)fx0;
        int y0c = min(max(y0, 0), 15), y1c = min(max(y0 + 1, 0), 15);
        int x0c = min(max(x0, 0), 15), x1c = min(max(x0 + 1, 0), 15);
        const float* e = emd + b * 256;
        float v00 = e[y0c * 16 + x0c], v01 = e[y0c * 16 + x1c];
        float v10 = e[y1c * 16 + x0c], v11 = e[y1c * 16 + x1c];
        out[idx] = (1.f - fy) * ((1.f - fx) * v00 + fx * v01)
                 + fy * ((1.f - fx) * v10 + fx * v11);
    }
}

extern "C" void kernel_launch(void* const* d_in, const int* in_sizes, int n_in,
                              void* d_out, int out_size, void* d_ws, size_t ws_size,
                              hipStream_t stream) {
    const float* ref = (const float*)d_in[0];
    const float* tgt = (const float*)d_in[1];
    float* out = (float*)d_out;

    float* lab = (float*)d_ws;                        // 1,572,864 f32
    float* bmn = lab + 2 * LAB_STRIDE;                // 768 f32
    float* bmx = bmn + 768;                           // 768 f32
    float* hr  = bmx + 768;                           // 524,288 f32
    float* ht  = hr + 524288;                         // 524,288 f32
    float* emd = ht + 524288;                         // 1024 f32
    _Float16* kmf = (_Float16*)(emd + 1024);          // 262,144 f16 (16B-aligned)
    _Float16* kcf = kmf + 262144;                     // 262,144 f16

    oklab_minmax_kernel<<<256, 256, 0, stream>>>(ref, tgt, lab, bmn, bmx);
    pack_hist_kernel<<<2048, 256, 0, stream>>>(lab, bmn, bmx, hr, ht, kmf, kcf);
    sinkhorn_kernel<<<128, 512, 0, stream>>>(hr, ht, kmf, kcf, emd);
    upsample_kernel<<<256, 256, 0, stream>>>(emd, out);
}

// Round 8
// 218.455 us; speedup vs baseline: 7.6795x; 1.0078x over previous
//
#include <hip/hip_runtime.h>
#include <hip/hip_bf16.h>

// ChromaticTransportEvaluator — round 8.
// R7 post-mortem: sinkhorn still L2-port-bound (416 KB/pass @ 119 GB/s/CU =
// 88% of per-CU port). K is iteration-invariant -> pin 7 kc-chunks in
// REGISTERS (112 VGPR/lane, loaded once), 3 chunks in LDS, stream only 6
// chunks (192 KB/pass) from L2. __launch_bounds__(512,2) caps 256 VGPR.
//
// mfma_f32_16x16x32_f16 layouts (shape-determined):
//   A[m][k]: m = lane&15, k = (lane>>4)*8 + reg
//   B[k][n]: n = lane&15, k = (lane>>4)*8 + reg
//   C/D:     col = lane&15, row = (lane>>4)*4 + reg

#define LAB_STRIDE 786432         // 4*3*256*256 floats per image-set
#define SP 520                    // f16 pitch for LDS u/v (multiple of 8)

typedef __attribute__((ext_vector_type(8))) _Float16 half8_t;
typedef __attribute__((ext_vector_type(4))) _Float16 half4_t;
typedef __attribute__((ext_vector_type(4))) float floatx4;

__device__ __forceinline__ float hw_exp2(float x) { return __builtin_amdgcn_exp2f(x); }
__device__ __forceinline__ float hw_log2(float x) { return __builtin_amdgcn_logf(x); }

__device__ __forceinline__ unsigned enc_f(float f) {
    unsigned u = __float_as_uint(f);
    return (u & 0x80000000u) ? ~u : (u | 0x80000000u);
}
__device__ __forceinline__ float dec_f(unsigned k) {
    unsigned u = (k & 0x80000000u) ? (k ^ 0x80000000u) : ~k;
    return __uint_as_float(u);
}

__device__ __forceinline__ float s2lin(float x) {
    x = fminf(fmaxf(x, 0.f), 1.f);
    return (x <= 0.04045f) ? (x * (1.f / 12.92f))
                           : hw_exp2(2.4f * hw_log2((x + 0.055f) * (1.f / 1.055f)));
}
__device__ __forceinline__ float cbrt_fast(float l) {
    return hw_exp2(0.33333333333f * hw_log2(fmaxf(l, 1e-12f)));
}

// Reduce per-block minmax (written by oklab) into lo/hi for image `img`.
__device__ __forceinline__ void compute_lohi(
        const float* __restrict__ bmn, const float* __restrict__ bmx,
        int img, float lo[3], float hi[3]) {
    int lane = threadIdx.x & 63;
    for (int c = 0; c < 3; ++c) {
        float mn = 3.4e38f, mx = -3.4e38f;
        for (int i = lane; i < 128; i += 64) {
            mn = fminf(mn, bmn[(img * 128 + i) * 3 + c]);
            mx = fmaxf(mx, bmx[(img * 128 + i) * 3 + c]);
        }
        for (int s = 1; s < 64; s <<= 1) {
            mn = fminf(mn, __shfl_xor(mn, s));
            mx = fmaxf(mx, __shfl_xor(mx, s));
        }
        float l = mn - 0.01f, h = mx + 0.01f;
        if (h - l < 1e-4f) { l -= 0.05f; h += 0.05f; }
        lo[c] = l; hi[c] = h;
    }
}

// 256 blocks x 256 threads x 8 px. img = blk>>7. Per-block minmax -> stores.
__global__ __launch_bounds__(256) void oklab_minmax_kernel(
        const float* __restrict__ ref, const float* __restrict__ tgt,
        float* __restrict__ lab, float* __restrict__ bmn, float* __restrict__ bmx) {
    int blk = blockIdx.x, tid = threadIdx.x;
    int img = blk >> 7;
    const float* src = img ? tgt : ref;
    float* dst = lab + img * LAB_STRIDE;

    __shared__ unsigned smin[3], smax[3];
    if (tid < 3) { smin[tid] = 0xFFFFFFFFu; smax[tid] = 0u; }
    __syncthreads();

    float fmn[3] = {3.4e38f, 3.4e38f, 3.4e38f};
    float fmx[3] = {-3.4e38f, -3.4e38f, -3.4e38f};
    int base = (blk & 127) * 2048;
    #pragma unroll
    for (int k = 0; k < 8; ++k) {
        int px = base + k * 256 + tid;          // 0..262143
        int bi = px >> 16, rem = px & 65535;
        float r = s2lin(src[(bi * 3 + 0) * 65536 + rem]);
        float g = s2lin(src[(bi * 3 + 1) * 65536 + rem]);
        float b = s2lin(src[(bi * 3 + 2) * 65536 + rem]);
        float l0 = fmaxf(0.4122214708f * r + 0.5363325363f * g + 0.0514459929f * b, 0.f);
        float l1 = fmaxf(0.2119034982f * r + 0.6806995451f * g + 0.1073969566f * b, 0.f);
        float l2 = fmaxf(0.0883024619f * r + 0.2817188376f * g + 0.6299787005f * b, 0.f);
        float g0 = (l0 > 0.f) ? cbrt_fast(l0) : 0.f;
        float g1 = (l1 > 0.f) ? cbrt_fast(l1) : 0.f;
        float g2 = (l2 > 0.f) ? cbrt_fast(l2) : 0.f;
        float L  = 0.2104542553f * g0 + 0.793617785f  * g1 - 0.0040720468f * g2;
        float A  = 1.9779984951f * g0 - 2.428592205f  * g1 + 0.4505937099f * g2;
        float Bv = 0.0259040371f * g0 + 0.7827717662f * g1 - 0.808675766f  * g2;
        dst[(bi * 3 + 0) * 65536 + rem] = L;
        dst[(bi * 3 + 1) * 65536 + rem] = A;
        dst[(bi * 3 + 2) * 65536 + rem] = Bv;
        fmn[0] = fminf(fmn[0], L);  fmx[0] = fmaxf(fmx[0], L);
        fmn[1] = fminf(fmn[1], A);  fmx[1] = fmaxf(fmx[1], A);
        fmn[2] = fminf(fmn[2], Bv); fmx[2] = fmaxf(fmx[2], Bv);
    }
    for (int s = 1; s < 64; s <<= 1) {
        for (int c = 0; c < 3; ++c) {
            fmn[c] = fminf(fmn[c], __shfl_xor(fmn[c], s));
            fmx[c] = fmaxf(fmx[c], __shfl_xor(fmx[c], s));
        }
    }
    if ((tid & 63) == 0) {
        for (int c = 0; c < 3; ++c) {
            atomicMin(&smin[c], enc_f(fmn[c]));
            atomicMax(&smax[c], enc_f(fmx[c]));
        }
    }
    __syncthreads();
    if (tid < 3) {
        bmn[blk * 3 + tid] = dec_f(smin[tid]);
        bmx[blk * 3 + tid] = dec_f(smax[tid]);
    }
}

// 2048 blocks x 256 thr: every block does 1 patch histogram; blocks 0..255
// also pack K as f16 B-fragments in [kc][jt][lane][8] order.
__global__ __launch_bounds__(256) void pack_hist_kernel(
        const float* __restrict__ lab,
        const float* __restrict__ bmn, const float* __restrict__ bmx,
        float* __restrict__ hr, float* __restrict__ ht,
        _Float16* __restrict__ kmf, _Float16* __restrict__ kcf) {
    int blk = blockIdx.x, tid = threadIdx.x;
    float lo0[3], hi0[3], lo1[3], hi1[3];
    compute_lohi(bmn, bmx, 0, lo0, hi0);
    compute_lohi(bmn, bmx, 1, lo1, hi1);

    if (blk < 256) {
        float cen[3][8];
        for (int c = 0; c < 3; ++c)
            for (int k = 0; k < 8; ++k) {
                float t = (k + 0.5f) * 0.125f;
                cen[c][k] = 0.5f * ((lo0[c] + (hi0[c] - lo0[c]) * t)
                                  + (lo1[c] + (hi1[c] - lo1[c]) * t));
            }
        int g = blk * 256 + tid;
        int half = g & 1, lane = (g >> 1) & 63, kc = (g >> 7) & 15, jt = g >> 11;
        int n = jt * 16 + (lane & 15);
        int kb = kc * 32 + ((lane >> 4) << 3) + half * 4;
        float n0 = cen[0][n >> 6], n1 = cen[1][(n >> 3) & 7], n2 = cen[2][n & 7];
        half4_t vm, vc;
        #pragma unroll
        for (int r = 0; r < 4; ++r) {
            int k = kb + r;
            float d0 = cen[0][k >> 6] - n0;
            float d1 = cen[1][(k >> 3) & 7] - n1;
            float d2 = cen[2][k & 7] - n2;
            float dd = d0 * d0 + d1 * d1 + d2 * d2;
            float cost = (dd > 0.f) ? __fsqrt_rn(dd) : 0.f;
            float kv = hw_exp2(-cost * 14.426950408889634f);   // exp(-cost/0.1)
            vm[r] = (_Float16)kv;
            vc[r] = (_Float16)(kv * cost);
        }
        int base = ((kc * 32 + jt) * 64 + lane) * 8 + half * 4;
        *(half4_t*)(kmf + base) = vm;
        *(half4_t*)(kcf + base) = vc;
    }

    // histogram: patch p of image-set img
    int img = blk >> 10;
    int p = blk & 1023;
    float cenI[3][8];
    {
        const float* lo = img ? lo1 : lo0;
        const float* hi = img ? hi1 : hi0;
        for (int c = 0; c < 3; ++c)
            for (int k = 0; k < 8; ++k)
                cenI[c][k] = lo[c] + (hi[c] - lo[c]) * ((k + 0.5f) * 0.125f);
    }
    __shared__ unsigned hcnt[512];
    hcnt[tid] = 0u; hcnt[tid + 256] = 0u;
    __syncthreads();
    int b = p >> 8, ph = (p >> 4) & 15, pw = p & 15;
    int y = tid >> 4, x = tid & 15;
    int rem = (ph * 16 + y) * 256 + (pw * 16 + x);
    const float* lb = lab + img * LAB_STRIDE;
    int kidx[3];
    for (int c = 0; c < 3; ++c) {
        float vv = lb[(b * 3 + c) * 65536 + rem];
        int best = 0; float bd = 3.4e38f;
        for (int k = 0; k < 8; ++k) {
            float d = vv - cenI[c][k];
            float ds = d * d;
            if (ds < bd) { bd = ds; best = k; }
        }
        kidx[c] = best;
    }
    atomicAdd(&hcnt[kidx[0] * 64 + kidx[1] * 8 + kidx[2]], 1u);
    __syncthreads();
    float* dst = img ? ht : hr;
    dst[p * 512 + tid]       = (float)hcnt[tid]       * (1.f / 256.f);
    dst[p * 512 + tid + 256] = (float)hcnt[tid + 256] * (1.f / 256.f);
}

// 128 blocks x 512 threads (8 waves). Block owns 8 patches, runs all 40
// half-iterations + EMD locally. u/v f16 in LDS. K residency per pass:
// kc 0..2 LDS (96 KB), kc 3..9 REGISTERS (112 VGPR/lane, loaded once),
// kc 10..15 streamed from L2 (192 KB). Wave w owns j-cols [w*64, w*64+64).
__global__ __launch_bounds__(512, 2) void sinkhorn_kernel(
        const float* __restrict__ hr, const float* __restrict__ ht,
        const _Float16* __restrict__ kmf, const _Float16* __restrict__ kcf,
        float* __restrict__ emd) {
    __shared__ __align__(16) _Float16 U[8 * SP], V[8 * SP];
    __shared__ __align__(16) _Float16 hrs[4096], hts[4096];
    __shared__ __align__(16) _Float16 Kc3[49152];   // kc 0..2 fragments, 96 KB
    __shared__ float ebuf[8];
    int tid = threadIdx.x;
    int wave = tid >> 6, lane = tid & 63;
    int pbase = blockIdx.x * 8;

    for (int i = tid; i < 4096; i += 512) {
        hrs[i] = (_Float16)hr[pbase * 512 + i];
        hts[i] = (_Float16)ht[pbase * 512 + i];
    }
    for (int i = tid; i < 8 * SP; i += 512) U[i] = (_Float16)1.0f;
    for (int i = tid; i < 6144; i += 512)
        *(half8_t*)(Kc3 + i * 8) = *(const half8_t*)(kmf + i * 8);
    if (tid < 8) ebuf[tid] = 0.f;

    int mrow = lane & 15;          // A row (patch)
    int kgrp = (lane >> 4) << 3;   // A k-offset
    int jt0 = wave * 4;            // first of 4 j-tiles for this wave
    int rq = lane >> 4;            // C row-quad
    int colc = lane & 15;          // C col

    // Pin kc 3..9 B-fragments in registers (7 chunks x 4 tiles x 4 VGPR).
    half8_t kreg[7][4];
    #pragma unroll
    for (int c = 0; c < 7; ++c)
        #pragma unroll
        for (int q = 0; q < 4; ++q)
            kreg[c][q] = *(const half8_t*)(kmf + (((c + 3) * 32 + jt0 + q) * 64 + lane) * 8);

    __syncthreads();

    for (int h = 0; h < 40; ++h) {
        const _Float16* S = (h & 1) ? V : U;
        _Float16* D = (h & 1) ? U : V;
        const _Float16* hs = (h & 1) ? hrs : hts;
        floatx4 acc[4] = {{0,0,0,0},{0,0,0,0},{0,0,0,0},{0,0,0,0}};
        #pragma unroll
        for (int kc = 0; kc < 3; ++kc) {       // LDS-cached chunks
            half8_t a = *(const half8_t*)&S[mrow * SP + kc * 32 + kgrp];
            #pragma unroll
            for (int q = 0; q < 4; ++q) {
                half8_t b = *(const half8_t*)&Kc3[((kc * 32 + jt0 + q) * 64 + lane) * 8];
                acc[q] = __builtin_amdgcn_mfma_f32_16x16x32_f16(a, b, acc[q], 0, 0, 0);
            }
        }
        #pragma unroll
        for (int kc = 3; kc < 10; ++kc) {      // register-pinned chunks
            half8_t a = *(const half8_t*)&S[mrow * SP + kc * 32 + kgrp];
            #pragma unroll
            for (int q = 0; q < 4; ++q)
                acc[q] = __builtin_amdgcn_mfma_f32_16x16x32_f16(a, kreg[kc - 3][q], acc[q], 0, 0, 0);
        }
        #pragma unroll
        for (int kc = 10; kc < 16; ++kc) {     // L2-streamed chunks
            half8_t a = *(const half8_t*)&S[mrow * SP + kc * 32 + kgrp];
            const _Float16* bb = kmf + ((kc * 32 + jt0) * 64 + lane) * 8;
            #pragma unroll
            for (int q = 0; q < 4; ++q) {
                half8_t b = *(const half8_t*)(bb + q * 512);
                acc[q] = __builtin_amdgcn_mfma_f32_16x16x32_f16(a, b, acc[q], 0, 0, 0);
            }
        }
        if (rq < 2) {
            #pragma unroll
            for (int q = 0; q < 4; ++q) {
                int col = (jt0 + q) * 16 + colc;
                #pragma unroll
                for (int r = 0; r < 4; ++r) {
                    int row = rq * 4 + r;
                    float d = (float)hs[row * 512 + col] / (acc[q][r] + 1e-6f);
                    D[row * SP + col] = (_Float16)fminf(d, 60000.f);
                }
            }
        }
        __syncthreads();
    }

    // EMD: acc = u @ Kc (f16, full L2 stream once), dot with v, reduce.
    {
        floatx4 acc[4] = {{0,0,0,0},{0,0,0,0},{0,0,0,0},{0,0,0,0}};
        #pragma unroll
        for (int kc = 0; kc < 16; ++kc) {
            half8_t a = *(const half8_t*)&U[mrow * SP + kc * 32 + kgrp];
            const _Float16* bb = kcf + ((kc * 32 + jt0) * 64 + lane) * 8;
            #pragma unroll
            for (int q = 0; q < 4; ++q) {
                half8_t b = *(const half8_t*)(bb + q * 512);
                acc[q] = __builtin_amdgcn_mfma_f32_16x16x32_f16(a, b, acc[q], 0, 0, 0);
            }
        }
        float pe[4] = {0.f, 0.f, 0.f, 0.f};
        if (rq < 2) {
            #pragma unroll
            for (int q = 0; q < 4; ++q) {
                int col = (jt0 + q) * 16 + colc;
                #pragma unroll
                for (int r = 0; r < 4; ++r)
                    pe[r] += acc[q][r] * (float)V[(rq * 4 + r) * SP + col];
            }
        }
        for (int s = 1; s < 16; s <<= 1) {
            #pragma unroll
            for (int r = 0; r < 4; ++r) pe[r] += __shfl_xor(pe[r], s);
        }
        if (colc == 0 && rq < 2) {
            #pragma unroll
            for (int r = 0; r < 4; ++r)
                atomicAdd(&ebuf[rq * 4 + r], pe[r]);
        }
        __syncthreads();
        if (tid < 8) {
            float e = ebuf[tid];
            emd[pbase + tid] = __builtin_isfinite(e) ? e : 0.f;
        }
    }
}

// (4,1,16,16) -> (4,1,256,256), half-pixel bilinear, edge clamp
__global__ __launch_bounds__(256) void upsample_kernel(
        const float* __restrict__ emd, float* __restrict__ out) {
    #pragma unroll
    for (int k = 0; k < 4; ++k) {
        int idx = blockIdx.x * 1024 + k * 256 + threadIdx.x;   // 0..262143
        int b = idx >> 16;
        int rem = idx & 65535;
        int y = rem >> 8, x = rem & 255;
        float sy = (y + 0.5f) * 0.0625f - 0.5f;
        float sx = (x + 0.5f) * 0.0625f - 0.5f;
        float fy0 = floorf(sy), fx0 = floorf(sx);
        float fy = sy - fy0, fx = sx - fx0;
        int y0 = (int)fy0, x0 = (int)fx0;
        int y0c = min(max(y0, 0), 15), y1c = min(max(y0 + 1, 0), 15);
        int x0c = min(max(x0, 0), 15), x1c = min(max(x0 + 1, 0), 15);
        const float* e = emd + b * 256;
        float v00 = e[y0c * 16 + x0c], v01 = e[y0c * 16 + x1c];
        float v10 = e[y1c * 16 + x0c], v11 = e[y1c * 16 + x1c];
        out[idx] = (1.f - fy) * ((1.f - fx) * v00 + fx * v01)
                 + fy * ((1.f - fx) * v10 + fx * v11);
    }
}

extern "C" void kernel_launch(void* const* d_in, const int* in_sizes, int n_in,
                              void* d_out, int out_size, void* d_ws, size_t ws_size,
                              hipStream_t stream) {
    const float* ref = (const float*)d_in[0];
    const float* tgt = (const float*)d_in[1];
    float* out = (float*)d_out;

    float* lab = (float*)d_ws;                        // 1,572,864 f32
    float* bmn = lab + 2 * LAB_STRIDE;                // 768 f32
    float* bmx = bmn + 768;                           // 768 f32
    float* hr  = bmx + 768;                           // 524,288 f32
    float* ht  = hr + 524288;                         // 524,288 f32
    float* emd = ht + 524288;                         // 1024 f32
    _Float16* kmf = (_Float16*)(emd + 1024);          // 262,144 f16 (16B-aligned)
    _Float16* kcf = kmf + 262144;                     // 262,144 f16

    oklab_minmax_kernel<<<256, 256, 0, stream>>>(ref, tgt, lab, bmn, bmx);
    pack_hist_kernel<<<2048, 256, 0, stream>>>(lab, bmn, bmx, hr, ht, kmf, kcf);
    sinkhorn_kernel<<<128, 512, 0, stream>>>(hr, ht, kmf, kcf, emd);
    upsample_kernel<<<256, 256, 0, stream>>>(emd, out);
}